// Round 1
// baseline (789.537 us; speedup 1.0000x reference)
//
#include <hip/hip_runtime.h>
#include <hip/hip_bf16.h>

// Problem: CliffordEPBottleneck — 10 relaxation steps of
//   rho = tanh(h); drive = W_sym @ rho + x; h = 0.9h + 0.1(1-rho^2)*drive
// B=256, nodes=4096, COMP=4. Core cost: 10x GEMM (1024 x 4096 x 4096) in bf16 MFMA.

#define BATCH   256
#define NODES   4096
#define MDIM    1024        // B*COMP
#define KDIM    4096
#define DLEN    16384       // NODES*COMP

typedef __attribute__((ext_vector_type(8))) __bf16 bf16x8;
typedef __attribute__((ext_vector_type(4))) float  f32x4;

static __device__ __forceinline__ unsigned short f32_to_bf16(float f) {
    unsigned int u = __float_as_uint(f);
    u += 0x7fffu + ((u >> 16) & 1u);   // round-to-nearest-even
    return (unsigned short)(u >> 16);
}

// ---------------------------------------------------------------------------
// Kernel 1: Wb[n][m] = bf16(0.5*(W[n][m] + W[m][n])), LDS-tiled so both global
// reads are coalesced. 64x64 tiles, 256 threads.
// ---------------------------------------------------------------------------
__global__ __launch_bounds__(256)
void symw_kernel(const float* __restrict__ W, unsigned short* __restrict__ Wb) {
    __shared__ float Ta[64][64];
    __shared__ float Tb[64][65];   // +1 pad: transposed read below
    const int tn = blockIdx.y, tm = blockIdx.x;
    const int c  = threadIdx.x & 63;
    const int r0 = threadIdx.x >> 6;   // 0..3
#pragma unroll
    for (int rr = 0; rr < 16; ++rr) {
        int r = r0 * 16 + rr;
        Ta[r][c] = W[(size_t)(tn * 64 + r) * 4096 + tm * 64 + c];
        Tb[r][c] = W[(size_t)(tm * 64 + r) * 4096 + tn * 64 + c];
    }
    __syncthreads();
#pragma unroll
    for (int rr = 0; rr < 16; ++rr) {
        int r = r0 * 16 + rr;
        float v = 0.5f * (Ta[r][c] + Tb[c][r]);
        Wb[(size_t)(tn * 64 + r) * 4096 + tm * 64 + c] = f32_to_bf16(v);
    }
}

// ---------------------------------------------------------------------------
// Kernel 2: h = x ; R0[(b*4+c), m] = bf16(tanh(x[b, m*4+c]))
// one thread per (b, m): float4 in, float4 out, 4 bf16 scattered (coalesced per c)
// ---------------------------------------------------------------------------
__global__ __launch_bounds__(256)
void init_kernel(const float* __restrict__ x, float* __restrict__ h,
                 unsigned short* __restrict__ R0) {
    int idx = blockIdx.x * blockDim.x + threadIdx.x;   // over B*NODES = 1M
    int b = idx >> 12;
    int m = idx & 4095;
    f32x4 xv = *(const f32x4*)(x + (size_t)idx * 4);
    *(f32x4*)(h + (size_t)idx * 4) = xv;
#pragma unroll
    for (int c = 0; c < 4; ++c) {
        R0[((size_t)(b * 4 + c)) * (size_t)KDIM + m] = f32_to_bf16(tanhf(xv[c]));
    }
}

// ---------------------------------------------------------------------------
// Kernel 3: one relaxation step.
//   GEMM: drive_rec[i][n] = sum_m Rcur[i][m] * Wb[n][m]   (i = b*4+c)
//   epilogue: hnew = 0.9h + 0.1(1-tanh(h)^2)*(drive_rec + x); h <- hnew;
//             Rnxt = bf16(tanh(hnew)); optionally out[b][n] = hnew(c=0)
// BM=64 BN=128 BK=64, 256 threads (4 waves, 2x2), wave = 32x64 output,
// 16x16x32 bf16 MFMA, global_load_lds width-16 staging, 2-barrier loop.
// ---------------------------------------------------------------------------
#define BM 64
#define BN 128
#define BK 64

__global__ __launch_bounds__(256, 2)
void step_kernel(const unsigned short* __restrict__ Rcur,
                 const unsigned short* __restrict__ Wb,
                 const float* __restrict__ x,
                 float* __restrict__ h,
                 unsigned short* __restrict__ Rnxt,
                 float* __restrict__ out) {
    __shared__ unsigned short As[BM * BK];   // 8 KB
    __shared__ unsigned short Bs[BN * BK];   // 16 KB

    const int tid  = threadIdx.x;
    const int bx   = blockIdx.x;           // n-tile (0..31)
    const int by   = blockIdx.y;           // m-tile (0..15)
    const int rowA0 = by * BM;
    const int rowB0 = bx * BN;

    const int w    = tid >> 6;
    const int lane = tid & 63;
    const int m0   = (w >> 1) * 32;
    const int n0   = (w & 1) * 64;
    const int lr   = lane & 15;
    const int lk   = lane >> 4;             // 0..3

    f32x4 acc[2][4];
#pragma unroll
    for (int mi = 0; mi < 2; ++mi)
#pragma unroll
        for (int ni = 0; ni < 4; ++ni)
            acc[mi][ni] = (f32x4){0.f, 0.f, 0.f, 0.f};

    for (int k0 = 0; k0 < KDIM; k0 += BK) {
        // stage A: 64x64 bf16 = 512 x 16B chunks, 2 per thread
#pragma unroll
        for (int j = 0; j < 2; ++j) {
            int chunk = tid + 256 * j;
            int row = chunk >> 3, cc = chunk & 7;
            const unsigned short* g = Rcur + (size_t)(rowA0 + row) * KDIM + k0 + cc * 8;
            __builtin_amdgcn_global_load_lds(
                (const __attribute__((address_space(1))) void*)g,
                (__attribute__((address_space(3))) void*)(As + chunk * 8), 16, 0, 0);
        }
        // stage B: 128x64 bf16 = 1024 chunks, 4 per thread
#pragma unroll
        for (int j = 0; j < 4; ++j) {
            int chunk = tid + 256 * j;
            int row = chunk >> 3, cc = chunk & 7;
            const unsigned short* g = Wb + (size_t)(rowB0 + row) * KDIM + k0 + cc * 8;
            __builtin_amdgcn_global_load_lds(
                (const __attribute__((address_space(1))) void*)g,
                (__attribute__((address_space(3))) void*)(Bs + chunk * 8), 16, 0, 0);
        }
        __syncthreads();   // drains vmcnt(0) then barrier

#pragma unroll
        for (int kk = 0; kk < 2; ++kk) {
            bf16x8 a[2], b[4];
#pragma unroll
            for (int mi = 0; mi < 2; ++mi)
                a[mi] = *(const bf16x8*)(As + (m0 + mi * 16 + lr) * BK + kk * 32 + lk * 8);
#pragma unroll
            for (int ni = 0; ni < 4; ++ni)
                b[ni] = *(const bf16x8*)(Bs + (n0 + ni * 16 + lr) * BK + kk * 32 + lk * 8);
#pragma unroll
            for (int mi = 0; mi < 2; ++mi)
#pragma unroll
                for (int ni = 0; ni < 4; ++ni)
                    acc[mi][ni] = __builtin_amdgcn_mfma_f32_16x16x32_bf16(
                        a[mi], b[ni], acc[mi][ni], 0, 0, 0);
        }
        __syncthreads();
    }

    // Epilogue. C/D layout: col = lane&15, row = (lane>>4)*4 + reg.
    // One lane's 4 regs = c=0..3 of a single (b, n) -> contiguous float4 in h/x.
#pragma unroll
    for (int mi = 0; mi < 2; ++mi) {
        int i0 = rowA0 + m0 + mi * 16 + lk * 4;   // multiple of 4
        int b  = i0 >> 2;
#pragma unroll
        for (int ni = 0; ni < 4; ++ni) {
            int n = rowB0 + n0 + ni * 16 + lr;
            size_t hidx = (size_t)b * DLEN + (size_t)n * 4;
            f32x4 h4 = *(const f32x4*)(h + hidx);
            f32x4 x4 = *(const f32x4*)(x + hidx);
            f32x4 hn;
#pragma unroll
            for (int r = 0; r < 4; ++r) {
                float hv   = h4[r];
                float rho  = tanhf(hv);
                float drive = acc[mi][ni][r] + x4[r];
                float hnew = 0.9f * hv + 0.1f * (1.0f - rho * rho) * drive;
                hn[r] = hnew;
                Rnxt[(size_t)(i0 + r) * KDIM + n] = f32_to_bf16(tanhf(hnew));
            }
            *(f32x4*)(h + hidx) = hn;
            if (out) out[(size_t)b * NODES + n] = hn[0];
        }
    }
}

// ---------------------------------------------------------------------------
extern "C" void kernel_launch(void* const* d_in, const int* in_sizes, int n_in,
                              void* d_out, int out_size, void* d_ws, size_t ws_size,
                              hipStream_t stream) {
    const float* x = (const float*)d_in[0];   // (256, 16384) f32
    const float* W = (const float*)d_in[1];   // (4096, 4096) f32
    float* out = (float*)d_out;               // (256, 4096) f32

    char* ws = (char*)d_ws;
    // ws layout: Wb 32MB | R0 8MB | R1 8MB | h 16MB  (total 64MB)
    unsigned short* Wb = (unsigned short*)(ws);
    unsigned short* R0 = (unsigned short*)(ws + ((size_t)32 << 20));
    unsigned short* R1 = (unsigned short*)(ws + ((size_t)40 << 20));
    float*          h  = (float*)(ws + ((size_t)48 << 20));

    symw_kernel<<<dim3(64, 64), 256, 0, stream>>>(W, Wb);
    init_kernel<<<dim3(4096), 256, 0, stream>>>(x, h, R0);

    unsigned short* rc = R0;
    unsigned short* rn = R1;
    for (int s = 0; s < 10; ++s) {
        step_kernel<<<dim3(32, 16), 256, 0, stream>>>(
            rc, Wb, x, h, rn, (s == 9) ? out : nullptr);
        unsigned short* t = rc; rc = rn; rn = t;
    }
}

// Round 2
// 632.232 us; speedup vs baseline: 1.2488x; 1.2488x over previous
//
#include <hip/hip_runtime.h>
#include <hip/hip_bf16.h>

// Problem: CliffordEPBottleneck — 10 relaxation steps of
//   rho = tanh(h); drive = W_sym @ rho + x; h = 0.9h + 0.1(1-rho^2)*drive
// B=256, nodes=4096, COMP=4. Core cost: 10x GEMM (1024 x 4096 x 4096) in bf16 MFMA.
//
// R2 change: XOR-swizzled LDS (both-sides: pre-swizzled global_load_lds source
// + swizzled ds_read address) to kill the 16-lane same-column bank conflicts
// measured in R1 (SQ_LDS_BANK_CONFLICT = 1.9e7/dispatch = 12 extra cyc/read).

#define BATCH   256
#define NODES   4096
#define MDIM    1024        // B*COMP
#define KDIM    4096
#define DLEN    16384       // NODES*COMP

typedef __attribute__((ext_vector_type(8))) __bf16 bf16x8;
typedef __attribute__((ext_vector_type(4))) float  f32x4;

static __device__ __forceinline__ unsigned short f32_to_bf16(float f) {
    unsigned int u = __float_as_uint(f);
    u += 0x7fffu + ((u >> 16) & 1u);   // round-to-nearest-even
    return (unsigned short)(u >> 16);
}

// ---------------------------------------------------------------------------
// Kernel 1: Wb[n][m] = bf16(0.5*(W[n][m] + W[m][n]))
// ---------------------------------------------------------------------------
__global__ __launch_bounds__(256)
void symw_kernel(const float* __restrict__ W, unsigned short* __restrict__ Wb) {
    __shared__ float Ta[64][64];
    __shared__ float Tb[64][65];   // +1 pad: transposed read below
    const int tn = blockIdx.y, tm = blockIdx.x;
    const int c  = threadIdx.x & 63;
    const int r0 = threadIdx.x >> 6;   // 0..3
#pragma unroll
    for (int rr = 0; rr < 16; ++rr) {
        int r = r0 * 16 + rr;
        Ta[r][c] = W[(size_t)(tn * 64 + r) * 4096 + tm * 64 + c];
        Tb[r][c] = W[(size_t)(tm * 64 + r) * 4096 + tn * 64 + c];
    }
    __syncthreads();
#pragma unroll
    for (int rr = 0; rr < 16; ++rr) {
        int r = r0 * 16 + rr;
        float v = 0.5f * (Ta[r][c] + Tb[c][r]);
        Wb[(size_t)(tn * 64 + r) * 4096 + tm * 64 + c] = f32_to_bf16(v);
    }
}

// ---------------------------------------------------------------------------
// Kernel 2: h = x ; R0[(b*4+c), m] = bf16(tanh(x[b, m*4+c]))
// ---------------------------------------------------------------------------
__global__ __launch_bounds__(256)
void init_kernel(const float* __restrict__ x, float* __restrict__ h,
                 unsigned short* __restrict__ R0) {
    int idx = blockIdx.x * blockDim.x + threadIdx.x;   // over B*NODES = 1M
    int b = idx >> 12;
    int m = idx & 4095;
    f32x4 xv = *(const f32x4*)(x + (size_t)idx * 4);
    *(f32x4*)(h + (size_t)idx * 4) = xv;
#pragma unroll
    for (int c = 0; c < 4; ++c) {
        R0[((size_t)(b * 4 + c)) * (size_t)KDIM + m] = f32_to_bf16(tanhf(xv[c]));
    }
}

// ---------------------------------------------------------------------------
// Kernel 3: one relaxation step. BM=64 BN=128 BK=64, 256 threads (4 waves),
// wave = 32x64 output, 16x16x32 bf16 MFMA, global_load_lds width-16 staging.
// LDS layout: each 64-row tile row holds 8 16B chunks; chunk slot is
// XOR-swizzled by (row & 7). Stage fetches the source chunk for the swizzled
// slot; reads XOR the slot index the same way -> conflict-free b128 reads.
// ---------------------------------------------------------------------------
#define BM 64
#define BN 128
#define BK 64

__global__ __launch_bounds__(256, 2)
void step_kernel(const unsigned short* __restrict__ Rcur,
                 const unsigned short* __restrict__ Wb,
                 const float* __restrict__ x,
                 float* __restrict__ h,
                 unsigned short* __restrict__ Rnxt,
                 float* __restrict__ out) {
    __shared__ unsigned short As[BM * BK];   // 8 KB
    __shared__ unsigned short Bs[BN * BK];   // 16 KB

    const int tid  = threadIdx.x;
    const int bx   = blockIdx.x;           // n-tile (0..31)
    const int by   = blockIdx.y;           // m-tile (0..15)
    const int rowA0 = by * BM;
    const int rowB0 = bx * BN;

    const int w    = tid >> 6;
    const int lane = tid & 63;
    const int m0   = (w >> 1) * 32;
    const int n0   = (w & 1) * 64;
    const int lr   = lane & 15;
    const int lk   = lane >> 4;             // 0..3

    f32x4 acc[2][4];
#pragma unroll
    for (int mi = 0; mi < 2; ++mi)
#pragma unroll
        for (int ni = 0; ni < 4; ++ni)
            acc[mi][ni] = (f32x4){0.f, 0.f, 0.f, 0.f};

    for (int k0 = 0; k0 < KDIM; k0 += BK) {
        // stage A: 64x64 bf16 = 512 x 16B chunks, 2 per thread.
        // LDS chunk (row, cs) receives global chunk (row, cs ^ (row&7)).
#pragma unroll
        for (int j = 0; j < 2; ++j) {
            int chunk = tid + 256 * j;
            int row = chunk >> 3, cs = chunk & 7;
            int cg = cs ^ (row & 7);
            const unsigned short* g = Rcur + (size_t)(rowA0 + row) * KDIM + k0 + cg * 8;
            __builtin_amdgcn_global_load_lds(
                (const __attribute__((address_space(1))) void*)g,
                (__attribute__((address_space(3))) void*)(As + chunk * 8), 16, 0, 0);
        }
        // stage B: 128x64 bf16 = 1024 chunks, 4 per thread
#pragma unroll
        for (int j = 0; j < 4; ++j) {
            int chunk = tid + 256 * j;
            int row = chunk >> 3, cs = chunk & 7;
            int cg = cs ^ (row & 7);
            const unsigned short* g = Wb + (size_t)(rowB0 + row) * KDIM + k0 + cg * 8;
            __builtin_amdgcn_global_load_lds(
                (const __attribute__((address_space(1))) void*)g,
                (__attribute__((address_space(3))) void*)(Bs + chunk * 8), 16, 0, 0);
        }
        __syncthreads();   // drains vmcnt(0) then barrier

#pragma unroll
        for (int kk = 0; kk < 2; ++kk) {
            bf16x8 a[2], b[4];
#pragma unroll
            for (int mi = 0; mi < 2; ++mi) {
                int row = m0 + mi * 16 + lr;
                int slot = (kk * 4 + lk) ^ (row & 7);
                a[mi] = *(const bf16x8*)(As + row * BK + slot * 8);
            }
#pragma unroll
            for (int ni = 0; ni < 4; ++ni) {
                int row = n0 + ni * 16 + lr;
                int slot = (kk * 4 + lk) ^ (row & 7);
                b[ni] = *(const bf16x8*)(Bs + row * BK + slot * 8);
            }
#pragma unroll
            for (int mi = 0; mi < 2; ++mi)
#pragma unroll
                for (int ni = 0; ni < 4; ++ni)
                    acc[mi][ni] = __builtin_amdgcn_mfma_f32_16x16x32_bf16(
                        a[mi], b[ni], acc[mi][ni], 0, 0, 0);
        }
        __syncthreads();
    }

    // Epilogue. C/D layout: col = lane&15, row = (lane>>4)*4 + reg.
    // One lane's 4 regs = c=0..3 of a single (b, n) -> contiguous float4 in h/x.
#pragma unroll
    for (int mi = 0; mi < 2; ++mi) {
        int i0 = rowA0 + m0 + mi * 16 + lk * 4;   // multiple of 4
        int b  = i0 >> 2;
#pragma unroll
        for (int ni = 0; ni < 4; ++ni) {
            int n = rowB0 + n0 + ni * 16 + lr;
            size_t hidx = (size_t)b * DLEN + (size_t)n * 4;
            f32x4 h4 = *(const f32x4*)(h + hidx);
            f32x4 x4 = *(const f32x4*)(x + hidx);
            f32x4 hn;
#pragma unroll
            for (int r = 0; r < 4; ++r) {
                float hv   = h4[r];
                float rho  = tanhf(hv);
                float drive = acc[mi][ni][r] + x4[r];
                float hnew = 0.9f * hv + 0.1f * (1.0f - rho * rho) * drive;
                hn[r] = hnew;
                Rnxt[(size_t)(i0 + r) * KDIM + n] = f32_to_bf16(tanhf(hnew));
            }
            *(f32x4*)(h + hidx) = hn;
            if (out) out[(size_t)b * NODES + n] = hn[0];
        }
    }
}

// ---------------------------------------------------------------------------
extern "C" void kernel_launch(void* const* d_in, const int* in_sizes, int n_in,
                              void* d_out, int out_size, void* d_ws, size_t ws_size,
                              hipStream_t stream) {
    const float* x = (const float*)d_in[0];   // (256, 16384) f32
    const float* W = (const float*)d_in[1];   // (4096, 4096) f32
    float* out = (float*)d_out;               // (256, 4096) f32

    char* ws = (char*)d_ws;
    // ws layout: Wb 32MB | R0 8MB | R1 8MB | h 16MB  (total 64MB)
    unsigned short* Wb = (unsigned short*)(ws);
    unsigned short* R0 = (unsigned short*)(ws + ((size_t)32 << 20));
    unsigned short* R1 = (unsigned short*)(ws + ((size_t)40 << 20));
    float*          h  = (float*)(ws + ((size_t)48 << 20));

    symw_kernel<<<dim3(64, 64), 256, 0, stream>>>(W, Wb);
    init_kernel<<<dim3(4096), 256, 0, stream>>>(x, h, R0);

    unsigned short* rc = R0;
    unsigned short* rn = R1;
    for (int s = 0; s < 10; ++s) {
        step_kernel<<<dim3(32, 16), 256, 0, stream>>>(
            rc, Wb, x, h, rn, (s == 9) ? out : nullptr);
        unsigned short* t = rc; rc = rn; rn = t;
    }
}